// Round 2
// baseline (382.849 us; speedup 1.0000x reference)
//
#include <hip/hip_runtime.h>

// StateSpaceDiffusionModel: y[b,h,:] = causal_conv(u[b,h,:], f[h,:])
// where f[h,s] = k_h^T M_h^s e1, M_h a column-normalized companion matrix.
//
// Collapsed scalar form per (b,h):
//   r_t = u_t + sum_{j=0}^{63} w[j] * r_{t-1-j}      (order-64 IIR)
//   y_t = sum_{j=0}^{63} g[j] * r_{t-j}              (order-64 FIR)
// with  kn = l1norm(clip(k,1/16,1)),  c_j = 1/(1+kn_j),  P_j = prod_{q<j} c_q,
//       w_j = kn_j*c_j*P_j (j<63), w_63 = P_63,  g_j = k_j*P_j.
// Chunked (64-wide) scan:  E = u + Hankel(w)*prev_window ; r = Toeplitz(s)*E,
// s = in-chunk impulse response (s_0=1, s_d = sum_{j<d} w_j s_{d-1-j}).
//
// Round 2: prologue rewritten shfl-free (LDS-sequential) to de-risk wave
// intrinsics; main loop identical to Round 1 (algebra verified on paper).

namespace {

constexpr int kCH = 512;        // C*H
constexpr int kL  = 2048;       // sequence length
constexpr int kN  = 64;         // state / chunk size
constexpr int kChunks = kL / kN;  // 32

__global__ __launch_bounds__(64, 2)
void ssm_scan_kernel(const float* __restrict__ u,
                     const float* __restrict__ kin,
                     float* __restrict__ y) {
  const int h  = blockIdx.x >> 2;       // head
  const int b0 = (blockIdx.x & 3) * 4;  // batch base
  const int i  = threadIdx.x;           // lane 0..63

  __shared__ __align__(16) float R2T[4][128];   // rolling r window per local b
  __shared__ __align__(16) float Elds[kN][8];   // E[mm][b-local], row stride 8
  __shared__ float wPad[128];   // wPad[j]=w_j (j<64), 0 for j in [64,128)
  __shared__ float sPad[128];   // sPad[64+d]=s_d, sPad[<64]=0
  __shared__ float gArr[kN];
  __shared__ float tmp[kN];

  // zero rolling window (visible after first barrier below)
  {
    float* r2 = &R2T[0][0];
    #pragma unroll
    for (int idx = 0; idx < 8; ++idx) r2[i + 64 * idx] = 0.0f;
  }

  // ---------------- prologue: per-head coefficients, shfl-free -------------
  const float kv = kin[h * kN + i];
  const float kc = fminf(fmaxf(kv, 0.0625f), 1.0f);
  tmp[i] = kc;
  __syncthreads();
  float ks = 0.0f;
  for (int j = 0; j < kN; ++j) ks += tmp[j];     // same order on every lane
  const float kn = kc / ks;
  const float cc = 1.0f / (1.0f + kn);
  __syncthreads();                                // all done reading tmp
  tmp[i] = cc;
  __syncthreads();
  float P = 1.0f;
  for (int j = 0; j < i; ++j) P *= tmp[j];       // exclusive prefix product
  const float w = (i < 63) ? (kn * cc * P) : P;
  wPad[i]      = w;
  wPad[kN + i] = 0.0f;
  gArr[i]      = kv * P;                          // original (unclipped) k
  sPad[i]      = 0.0f;
  if (i == 0) sPad[kN] = 1.0f;                    // s_0 = 1
  __syncthreads();

  // impulse response s_1..s_63 via LDS systolic: at iter rr, s_rr is final;
  // every lane folds w_{i-1-rr} * s_rr into its own accumulator; lane rr+1
  // publishes s_{rr+1}. Write targets cell kN+rr+1, reads cell kN+rr: no race.
  float acc = (i == 0) ? 1.0f : 0.0f;
  for (int rr = 0; rr < kN - 1; ++rr) {
    const float sval = sPad[kN + rr];
    const float coef = (i > rr) ? wPad[i - 1 - rr] : 0.0f;
    acc = fmaf(coef, sval, acc);
    if (i == rr + 1) sPad[kN + i] = acc;
    __syncthreads();
  }

  // per-lane coefficient rows (registers)
  float wRow[kN];   // wRow[p] = wPad[i + 63 - p]   (Hankel row for E-phase)
  float sRow[kN];   // sRow[mm] = sPad[64 + i - mm] (Toeplitz row for r-phase)
  #pragma unroll
  for (int p = 0; p < kN; ++p) wRow[p] = wPad[i + 63 - p];
  #pragma unroll
  for (int mm = 0; mm < kN; ++mm) sRow[mm] = sPad[kN + i - mm];

  const size_t bstride = (size_t)kCH * kL;
  const size_t hbase   = (size_t)h * kL;
  const float* uu0 = u + (size_t)(b0 + 0) * bstride + hbase + i;
  const float* uu1 = u + (size_t)(b0 + 1) * bstride + hbase + i;
  const float* uu2 = u + (size_t)(b0 + 2) * bstride + hbase + i;
  const float* uu3 = u + (size_t)(b0 + 3) * bstride + hbase + i;
  float* yy0 = y + (size_t)(b0 + 0) * bstride + hbase + i;
  float* yy1 = y + (size_t)(b0 + 1) * bstride + hbase + i;
  float* yy2 = y + (size_t)(b0 + 2) * bstride + hbase + i;
  float* yy3 = y + (size_t)(b0 + 3) * bstride + hbase + i;

  for (int m = 0; m < kChunks; ++m) {
    const int t0 = m * kN;
    // issue global loads early
    const float uv0 = uu0[t0];
    const float uv1 = uu1[t0];
    const float uv2 = uu2[t0];
    const float uv3 = uu3[t0];

    // ---- E-phase: E[i][b] = u + sum_p wRow[p] * prev_window[p][b] ----------
    const int prow = (t0 + 64) & 127;   // start of previous chunk's rows
    const float4* q0 = (const float4*)&R2T[0][prow];
    const float4* q1 = (const float4*)&R2T[1][prow];
    const float4* q2 = (const float4*)&R2T[2][prow];
    const float4* q3 = (const float4*)&R2T[3][prow];
    float e0 = 0.f, e1 = 0.f, e2 = 0.f, e3 = 0.f;
    #pragma unroll
    for (int p4 = 0; p4 < 16; ++p4) {
      const float4 v0 = q0[p4];
      const float4 v1 = q1[p4];
      const float4 v2 = q2[p4];
      const float4 v3 = q3[p4];
      const float w0 = wRow[4 * p4 + 0];
      const float w1 = wRow[4 * p4 + 1];
      const float w2 = wRow[4 * p4 + 2];
      const float w3 = wRow[4 * p4 + 3];
      e0 = fmaf(w0, v0.x, e0); e0 = fmaf(w1, v0.y, e0);
      e0 = fmaf(w2, v0.z, e0); e0 = fmaf(w3, v0.w, e0);
      e1 = fmaf(w0, v1.x, e1); e1 = fmaf(w1, v1.y, e1);
      e1 = fmaf(w2, v1.z, e1); e1 = fmaf(w3, v1.w, e1);
      e2 = fmaf(w0, v2.x, e2); e2 = fmaf(w1, v2.y, e2);
      e2 = fmaf(w2, v2.z, e2); e2 = fmaf(w3, v2.w, e2);
      e3 = fmaf(w0, v3.x, e3); e3 = fmaf(w1, v3.y, e3);
      e3 = fmaf(w2, v3.z, e3); e3 = fmaf(w3, v3.w, e3);
    }
    e0 += uv0; e1 += uv1; e2 += uv2; e3 += uv3;
    float4 ev; ev.x = e0; ev.y = e1; ev.z = e2; ev.w = e3;
    *(float4*)&Elds[i][0] = ev;
    __syncthreads();

    // ---- r-phase: r[i][b] = sum_mm sRow[mm] * E[mm][b] ---------------------
    float rr0 = 0.f, rr1 = 0.f, rr2 = 0.f, rr3 = 0.f;
    #pragma unroll
    for (int mm = 0; mm < kN; ++mm) {
      const float4 evv = *(const float4*)&Elds[mm][0];
      const float sm = sRow[mm];
      rr0 = fmaf(sm, evv.x, rr0);
      rr1 = fmaf(sm, evv.y, rr1);
      rr2 = fmaf(sm, evv.z, rr2);
      rr3 = fmaf(sm, evv.w, rr3);
    }
    const int crow = (t0 & 127) + i;
    R2T[0][crow] = rr0;
    R2T[1][crow] = rr1;
    R2T[2][crow] = rr2;
    R2T[3][crow] = rr3;
    __syncthreads();

    // ---- y-phase: y[t0+i][b] = sum_j g[j] * r[t0+i-j][b] -------------------
    float a0 = 0.f, a1 = 0.f, a2 = 0.f, a3 = 0.f;
    const int base = t0 + i + 128;
    #pragma unroll
    for (int j = 0; j < kN; ++j) {
      const float gj  = gArr[j];
      const int  row  = (base - j) & 127;
      a0 = fmaf(gj, R2T[0][row], a0);
      a1 = fmaf(gj, R2T[1][row], a1);
      a2 = fmaf(gj, R2T[2][row], a2);
      a3 = fmaf(gj, R2T[3][row], a3);
    }
    yy0[t0] = a0;
    yy1[t0] = a1;
    yy2[t0] = a2;
    yy3[t0] = a3;
    // next chunk's r-writes are gated by its post-E barrier, which orders
    // them after this chunk's y-reads.
  }
}

}  // namespace

extern "C" void kernel_launch(void* const* d_in, const int* in_sizes, int n_in,
                              void* d_out, int out_size, void* d_ws, size_t ws_size,
                              hipStream_t stream) {
  const float* u  = (const float*)d_in[0];   // (16, 512, 2048) fp32
  const float* kk = (const float*)d_in[1];   // (1, 512, 64)    fp32
  if (n_in >= 2 && in_sizes[0] < in_sizes[1]) {  // defensive: order by size
    const float* t = u; u = kk; kk = t;
  }
  float* y = (float*)d_out;                  // (16, 512, 2048) fp32
  // one wave per (head, batch-quad): 512 heads * 4 quads = 2048 blocks
  hipLaunchKernelGGL(ssm_scan_kernel, dim3(kCH * 4), dim3(64), 0, stream,
                     u, kk, y);
}

// Round 3
// 146.101 us; speedup vs baseline: 2.6204x; 2.6204x over previous
//
#include <hip/hip_runtime.h>

// StateSpaceDiffusionModel — MFMA formulation.
//
// Scalar collapse (HW-verified in Round 2):
//   r_t = u_t + sum_{j=0}^{63} w_j r_{t-1-j},   y_t = sum_{j=0}^{63} g_j r_{t-j}
// Chunked by 64, per chunk (p = previous chunk's r window, 64x16 over batches):
//   E = u + W·p        W[i][j] = w[(i-j)+63]      (upper-tri Toeplitz)
//   r = S·E            S[i][j] = s[i-j]           (lower-tri Toeplitz, s = IIR impulse resp.)
//   y = G2·r + G1·p    G2[i][j] = g[i-j],  G1[i][j] = g[(i-j)+64]
// All four operators are Toeplitz -> A-fragments generated from 128-tap arrays,
// held in registers. Data path uses hi/lo split bf16 (3 MFMAs per product) for
// fp32-like accuracy; u enters exactly through the fp32 accumulator init.
// One workgroup (4 waves) per head; wave q owns output rows [16q,16q+16);
// batch dim (16) = MFMA N dim. mfma_f32_16x16x32_bf16 layouts per m89/m120:
//   A[m][k]: m=lane&15, k=(lane>>4)*8+j;  B[k][n]: k=(lane>>4)*8+j, n=lane&15;
//   C[m][n]: n=lane&15, m=(lane>>4)*4+reg.

namespace {

constexpr int kH = 512;
constexpr int kL = 2048;
constexpr int kChunks = 32;
constexpr int kStride = 68;   // LDS row stride (floats): 68 = 4*17, 2-way banks max

typedef __attribute__((ext_vector_type(8))) short bf16x8;
typedef __attribute__((ext_vector_type(4))) float f32x4;

__device__ inline unsigned short f32_to_bf16_rne(float x) {
  unsigned int u = __float_as_uint(x);
  unsigned int r = u + 0x7FFFu + ((u >> 16) & 1u);
  return (unsigned short)(r >> 16);
}
__device__ inline float bf16_as_f32(unsigned short h) {
  return __uint_as_float(((unsigned int)h) << 16);
}
// split 8 fp32 (two f32x4) into hi/lo bf16 fragments
__device__ inline void cvt_split8(const f32x4 a, const f32x4 b, bf16x8& fh, bf16x8& fl) {
  #pragma unroll
  for (int j = 0; j < 4; ++j) {
    unsigned short hi = f32_to_bf16_rne(a[j]);
    fh[j] = (short)hi;
    fl[j] = (short)f32_to_bf16_rne(a[j] - bf16_as_f32(hi));
  }
  #pragma unroll
  for (int j = 0; j < 4; ++j) {
    unsigned short hi = f32_to_bf16_rne(b[j]);
    fh[4 + j] = (short)hi;
    fl[4 + j] = (short)f32_to_bf16_rne(b[j] - bf16_as_f32(hi));
  }
}

#define MFMA(A, B, C) __builtin_amdgcn_mfma_f32_16x16x32_bf16((A), (B), (C), 0, 0, 0)

__global__ __launch_bounds__(256, 2)
void ssm_mfma_kernel(const float* __restrict__ u,
                     const float* __restrict__ kin,
                     float* __restrict__ y) {
  const int h    = blockIdx.x;
  const int tid  = threadIdx.x;
  const int wq   = tid >> 6;     // wave id = output row block
  const int lane = tid & 63;
  const int ln16 = lane & 15;    // batch col (B/C) / row m (A)
  const int quad = lane >> 4;

  __shared__ float taps[4][128];            // 0=W, 1=S, 2=G2, 3=G1
  __shared__ float Ebuf[16][kStride];       // [batch][time-in-chunk]
  __shared__ float Rbuf[16][kStride];
  __shared__ float tmpA[64], cArr[64], wArr[64], gArr[64], sArr[64];

  // ---------------- prologue: w, s, g (LDS-sequential, HW-verified) --------
  float kv = 0.f, kc = 0.f, kn = 0.f, cc = 0.f;
  if (tid < 64) {
    kv = kin[h * 64 + tid];
    kc = fminf(fmaxf(kv, 0.0625f), 1.0f);
    tmpA[tid] = kc;
  }
  __syncthreads();
  if (tid < 64) {
    float ks = 0.f;
    for (int j = 0; j < 64; ++j) ks += tmpA[j];
    kn = kc / ks;
    cc = 1.0f / (1.0f + kn);
    cArr[tid] = cc;
  }
  __syncthreads();
  if (tid < 64) {
    float P = 1.0f;
    for (int j = 0; j < tid; ++j) P *= cArr[j];
    wArr[tid] = (tid < 63) ? (kn * cc * P) : P;
    gArr[tid] = kv * P;
    if (tid == 0) sArr[0] = 1.0f;
  }
  __syncthreads();
  // impulse response s_1..s_63, LDS systolic (barrier per step)
  float acc_s = (tid == 0) ? 1.0f : 0.0f;
  for (int rr = 0; rr < 63; ++rr) {
    if (tid < 64) {
      const float sval = sArr[rr];
      const float coef = (tid > rr) ? wArr[tid - 1 - rr] : 0.0f;
      acc_s = fmaf(coef, sval, acc_s);
      if (tid == rr + 1) sArr[tid] = acc_s;
    }
    __syncthreads();
  }
  // tap arrays: index n = (i-j)+63 in [0,126]
  if (tid < 128) {
    const int n = tid;
    taps[0][n] = (n < 64) ? wArr[n] : 0.0f;        // W: w[(i-j)+63] == w[n], n<64
    taps[1][n] = (n >= 63) ? sArr[n - 63] : 0.0f;  // S: s[i-j]
    taps[2][n] = (n >= 63) ? gArr[n - 63] : 0.0f;  // G2: g[i-j]
    taps[3][n] = (n < 63) ? gArr[n + 1] : 0.0f;    // G1: g[(i-j)+64], i<j
  }
  __syncthreads();

  // ---------------- A-fragments from taps (registers, one-time) -----------
  bf16x8 fragH[4][2], fragL[4][2];
  #pragma unroll
  for (int mi = 0; mi < 4; ++mi) {
    #pragma unroll
    for (int tk = 0; tk < 2; ++tk) {
      const int n0 = 16 * wq + ln16 - (32 * tk + 8 * quad) + 63;
      bf16x8 fh, fl;
      #pragma unroll
      for (int j = 0; j < 8; ++j) {
        const int n = n0 - j;
        const float v = (n >= 0 && n < 127) ? taps[mi][n] : 0.0f;
        const unsigned short hi = f32_to_bf16_rne(v);
        fh[j] = (short)hi;
        fl[j] = (short)f32_to_bf16_rne(v - bf16_as_f32(hi));
      }
      fragH[mi][tk] = fh;
      fragL[mi][tk] = fl;
    }
  }

  // ---------------- main chunk loop ----------------------------------------
  bf16x8 pH[2], pL[2];
  {
    bf16x8 z;
    #pragma unroll
    for (int j = 0; j < 8; ++j) z[j] = 0;
    pH[0] = z; pH[1] = z; pL[0] = z; pL[1] = z;
  }

  // per-lane global base: batch = ln16, time offset = 16*wq + 4*quad
  const size_t gbase = ((size_t)ln16 * kH + h) * kL + 16 * wq + 4 * quad;
  const float* uptr = u + gbase;
  float* yptr = y + gbase;
  const int ewrow = 16 * wq + 4 * quad;   // C-layout write offset (time)

  f32x4 unext = *(const f32x4*)(uptr);    // prefetch chunk 0

  for (int m = 0; m < kChunks; ++m) {
    const int t0 = m * 64;
    const f32x4 ucur = unext;
    if (m + 1 < kChunks) unext = *(const f32x4*)(uptr + (m + 1) * 64);

    // accY = G1·p  (independent of E chain — schedule first)
    f32x4 accY = {};
    #pragma unroll
    for (int tk = 0; tk < 2; ++tk) {
      accY = MFMA(fragH[3][tk], pH[tk], accY);
      accY = MFMA(fragH[3][tk], pL[tk], accY);
      accY = MFMA(fragL[3][tk], pH[tk], accY);
    }
    // accE = u + W·p   (u exact via accumulator init)
    f32x4 accE = ucur;
    #pragma unroll
    for (int tk = 0; tk < 2; ++tk) {
      accE = MFMA(fragH[0][tk], pH[tk], accE);
      accE = MFMA(fragH[0][tk], pL[tk], accE);
      accE = MFMA(fragL[0][tk], pH[tk], accE);
    }
    *(f32x4*)&Ebuf[ln16][ewrow] = accE;
    __syncthreads();

    // E B-fragments (hi/lo)
    bf16x8 eH[2], eL[2];
    #pragma unroll
    for (int tk = 0; tk < 2; ++tk) {
      const int k0 = 8 * quad + 32 * tk;
      const f32x4 a = *(const f32x4*)&Ebuf[ln16][k0];
      const f32x4 b = *(const f32x4*)&Ebuf[ln16][k0 + 4];
      cvt_split8(a, b, eH[tk], eL[tk]);
    }
    // r = S·E
    f32x4 accR = {};
    #pragma unroll
    for (int tk = 0; tk < 2; ++tk) {
      accR = MFMA(fragH[1][tk], eH[tk], accR);
      accR = MFMA(fragH[1][tk], eL[tk], accR);
      accR = MFMA(fragL[1][tk], eH[tk], accR);
    }
    *(f32x4*)&Rbuf[ln16][ewrow] = accR;
    __syncthreads();

    // r fragments = next chunk's p fragments (read once, used twice)
    #pragma unroll
    for (int tk = 0; tk < 2; ++tk) {
      const int k0 = 8 * quad + 32 * tk;
      const f32x4 a = *(const f32x4*)&Rbuf[ln16][k0];
      const f32x4 b = *(const f32x4*)&Rbuf[ln16][k0 + 4];
      cvt_split8(a, b, pH[tk], pL[tk]);
    }
    // accY += G2·r
    #pragma unroll
    for (int tk = 0; tk < 2; ++tk) {
      accY = MFMA(fragH[2][tk], pH[tk], accY);
      accY = MFMA(fragH[2][tk], pL[tk], accY);
      accY = MFMA(fragL[2][tk], pH[tk], accY);
    }
    *(f32x4*)(yptr + t0) = accY;
    // Ebuf/Rbuf reuse is safe single-buffered: next writes sit after the next
    // __syncthreads, which orders them past this chunk's reads.
  }
}

}  // namespace

extern "C" void kernel_launch(void* const* d_in, const int* in_sizes, int n_in,
                              void* d_out, int out_size, void* d_ws, size_t ws_size,
                              hipStream_t stream) {
  const float* u  = (const float*)d_in[0];   // (16, 512, 2048) fp32
  const float* kk = (const float*)d_in[1];   // (1, 512, 64)    fp32
  if (n_in >= 2 && in_sizes[0] < in_sizes[1]) {
    const float* t = u; u = kk; kk = t;
  }
  float* y = (float*)d_out;                  // (16, 512, 2048) fp32
  hipLaunchKernelGGL(ssm_mfma_kernel, dim3(kH), dim3(256), 0, stream, u, kk, y);
}